// Round 1
// baseline (616.444 us; speedup 1.0000x reference)
//
#include <hip/hip_runtime.h>

// MoE fused kernel, MI355X gfx950.
// Shapes: B=65536, D=512, C=101, E=8, H=256.
// out[b,c] = sum_{e,h} g[b,e]*relu(x@W1+b1)[b,e,h]*W2[e,h,c] + sum_e g[b,e]*b2[e,c]
// g = softmax(x@Wg+bg). Gate logits folded into layer1 GEMM as cols 2048..2055.
// All matmuls in bf16 MFMA (16x16x32), fp32 accumulate.
//
// MFMA layouts (m89/m120-verified):
//   A: A[m][k], m=lane&15, k=(lane>>4)*8+j (j=0..7)
//   B: B[k][n], n=lane&15, k=(lane>>4)*8+j
//   C/D: col=lane&15, row=(lane>>4)*4+reg

typedef __attribute__((ext_vector_type(8))) short short8x;
typedef __attribute__((ext_vector_type(4))) float float4x;

#define C_DIM 101

__device__ __forceinline__ unsigned short f2bf(float f) {
  unsigned int u = __builtin_bit_cast(unsigned int, f);
  u += 0x7fffu + ((u >> 16) & 1u);     // round-to-nearest-even
  return (unsigned short)(u >> 16);
}

// ---- W1 (+Wg) -> bf16, B-frag packed: frag = ntile*16+kf ; elem = frag*512 + lane*8 + j
// ntile 0..128 (129 tiles of 16 cols: 2048 h-cols, 8 gate cols, 8 zero); kf 0..15 (K=512)
__global__ void conv_w1(const float* __restrict__ W1, const float* __restrict__ Wg,
                        unsigned short* __restrict__ out) {
  int s = blockIdx.x * blockDim.x + threadIdx.x;   // slot = frag*64 + lane
  int l = s & 63;
  int frag = s >> 6;
  int kf = frag & 15;
  int ntile = frag >> 4;
  int n = (ntile << 4) | (l & 15);
  int k = (kf << 5) | ((l >> 4) << 3);
  short8x v;
#pragma unroll
  for (int j = 0; j < 8; ++j) {
    int kk = k + j;
    float f;
    if (n < 2048)      f = W1[((size_t)(n >> 8) * 512 + kk) * 256 + (n & 255)];
    else if (n < 2056) f = Wg[(size_t)kk * 8 + (n - 2048)];
    else               f = 0.f;
    v[j] = (short)f2bf(f);
  }
  *(short8x*)(out + (size_t)s * 8) = v;
}

// ---- W2 -> bf16, B-frag packed: frag = ntile*64+kf ; ntile 0..7 (128 cols, 101 real), kf 0..63 (K=2048)
__global__ void conv_w2(const float* __restrict__ W2, unsigned short* __restrict__ out) {
  int s = blockIdx.x * blockDim.x + threadIdx.x;
  int l = s & 63;
  int frag = s >> 6;
  int kf = frag & 63;
  int ntile = frag >> 6;
  int c = (ntile << 4) | (l & 15);
  int k = (kf << 5) | ((l >> 4) << 3);
  short8x v;
#pragma unroll
  for (int j = 0; j < 8; ++j) {
    int kk = k + j;                       // e = kk>>8, h = kk&255
    float f = (c < C_DIM) ? W2[((size_t)(kk >> 8) * 256 + (kk & 255)) * C_DIM + c] : 0.f;
    v[j] = (short)f2bf(f);
  }
  *(short8x*)(out + (size_t)s * 8) = v;
}

// ---- fused main kernel: 32 rows/block, 256 threads (4 waves)
__global__ __launch_bounds__(256) void moe_main(
    const float* __restrict__ x, const float* __restrict__ b1,
    const float* __restrict__ b2, const float* __restrict__ bg,
    const unsigned short* __restrict__ W1bf, const unsigned short* __restrict__ W2bf,
    float* __restrict__ out) {
  __shared__ unsigned short xA[2 * 16 * 64 * 8];   // 32 KB: x, A-frag packed [mt][kf][lane][8]
  __shared__ unsigned short hA[2 * 8 * 64 * 8];    // 16 KB: h' N-tile, A-frag packed [mt][kf2][lane][8]
  __shared__ float gates[32][8];

  const int tid = threadIdx.x;
  const int w = tid >> 6;     // wave 0..3
  const int l = tid & 63;     // lane
  const int r0 = blockIdx.x * 32;

  // ---- stage x -> bf16 A-frag LDS (coalesced float4 x2 reads, b128 LDS writes)
#pragma unroll
  for (int it = 0; it < 8; ++it) {
    int g = tid + it * 256;            // 2048 groups of 8: m = g>>6, k0 = (g&63)*8
    int m = g >> 6;
    int k0 = (g & 63) << 3;
    const float* src = x + (size_t)(r0 + m) * 512 + k0;
    float4 f0 = *(const float4*)src;
    float4 f1 = *(const float4*)(src + 4);
    short8x v;
    v[0] = (short)f2bf(f0.x); v[1] = (short)f2bf(f0.y);
    v[2] = (short)f2bf(f0.z); v[3] = (short)f2bf(f0.w);
    v[4] = (short)f2bf(f1.x); v[5] = (short)f2bf(f1.y);
    v[6] = (short)f2bf(f1.z); v[7] = (short)f2bf(f1.w);
    int mt = m >> 4;
    int kfrag = k0 >> 5;
    int lane = (((k0 >> 3) & 3) << 4) | (m & 15);
    *(short8x*)&xA[(size_t)(((mt << 4) | kfrag) * 64 + lane) * 8] = v;
  }
  __syncthreads();

  // ---- gate logits: waves 0,1 each do one 16-row tile x 16 gate cols (ntile 128)
  if (w < 2) {
    float4x acc = {0.f, 0.f, 0.f, 0.f};
    for (int kf = 0; kf < 16; ++kf) {
      short8x a = *(const short8x*)&xA[(size_t)((w * 16 + kf) * 64 + l) * 8];
      short8x b = *(const short8x*)(W1bf + ((size_t)(128 * 16 + kf) * 512 + l * 8));
      acc = __builtin_amdgcn_mfma_f32_16x16x32_bf16(a, b, acc, 0, 0, 0);
    }
    int col = l & 15;
    if (col < 8) {
      float bgv = bg[col];
#pragma unroll
      for (int r = 0; r < 4; ++r) {
        int row = ((l >> 4) << 2) + r;
        gates[w * 16 + row][col] = acc[r] + bgv;
      }
    }
  }
  __syncthreads();
  // softmax over E=8 per row, fp32
  if (tid < 32) {
    float v[8], mx = -1e30f;
#pragma unroll
    for (int e = 0; e < 8; ++e) { v[e] = gates[tid][e]; mx = fmaxf(mx, v[e]); }
    float s = 0.f;
#pragma unroll
    for (int e = 0; e < 8; ++e) { v[e] = expf(v[e] - mx); s += v[e]; }
    float inv = 1.f / s;
#pragma unroll
    for (int e = 0; e < 8; ++e) gates[tid][e] = v[e] * inv;
  }
  __syncthreads();

  // ---- main loop over 8 N-tiles of 256 h-columns
  float4x zero = {0.f, 0.f, 0.f, 0.f};
  float4x acc2[2][2];                    // layer2 out: rows mt*16.., cols (2w+ct)*16..
  acc2[0][0] = zero; acc2[0][1] = zero; acc2[1][0] = zero; acc2[1][1] = zero;

  for (int nt = 0; nt < 8; ++nt) {
    // layer1: wave w covers cols [w*64, w*64+64) of this N-tile; all 32 rows
    float4x acc1[2][4];
    acc1[0][0] = zero; acc1[0][1] = zero; acc1[0][2] = zero; acc1[0][3] = zero;
    acc1[1][0] = zero; acc1[1][1] = zero; acc1[1][2] = zero; acc1[1][3] = zero;
#pragma unroll 4
    for (int kf = 0; kf < 16; ++kf) {
      short8x a0 = *(const short8x*)&xA[(size_t)((0 * 16 + kf) * 64 + l) * 8];
      short8x a1 = *(const short8x*)&xA[(size_t)((1 * 16 + kf) * 64 + l) * 8];
#pragma unroll
      for (int nc = 0; nc < 4; ++nc) {
        int ntile = nt * 16 + w * 4 + nc;
        short8x b = *(const short8x*)(W1bf + ((size_t)(ntile * 16 + kf) * 512 + l * 8));
        acc1[0][nc] = __builtin_amdgcn_mfma_f32_16x16x32_bf16(a0, b, acc1[0][nc], 0, 0, 0);
        acc1[1][nc] = __builtin_amdgcn_mfma_f32_16x16x32_bf16(a1, b, acc1[1][nc], 0, 0, 0);
      }
    }
    __syncthreads();   // previous iteration's layer2 readers done with hA
    // epilogue: +b1, relu, *gate, bf16 -> hA in A-frag layout (C->A transpose)
#pragma unroll
    for (int nc = 0; nc < 4; ++nc) {
      int n = nt * 256 + w * 64 + nc * 16 + (l & 15);   // global h-col 0..2047
      float b1v = b1[n];                                 // b1 flat [E*H] == [n]
      int e = n >> 8;
      int kfrag2 = (w << 1) | (nc >> 1);                 // (col_in_tile)>>5
      int chunk = ((nc & 1) << 1) | ((l >> 3) & 1);      // ((col_in_tile)>>3)&3
      int j = l & 7;
#pragma unroll
      for (int mt = 0; mt < 2; ++mt) {
#pragma unroll
        for (int r = 0; r < 4; ++r) {
          int row = ((l >> 4) << 2) + r;                 // C-layout row in 16x16 tile
          float gv = gates[mt * 16 + row][e];
          float hv = fmaxf(acc1[mt][nc][r] + b1v, 0.f) * gv;
          hA[(size_t)(((mt * 8 + kfrag2) * 64) + (chunk << 4) + row) * 8 + j] = f2bf(hv);
        }
      }
    }
    __syncthreads();
    // layer2 partial: K-chunk = this N-tile's 256 h-cols; wave w -> col-tiles {2w, 2w+1}
#pragma unroll 4
    for (int kk = 0; kk < 8; ++kk) {
      short8x a0 = *(const short8x*)&hA[(size_t)((0 * 8 + kk) * 64 + l) * 8];
      short8x a1 = *(const short8x*)&hA[(size_t)((1 * 8 + kk) * 64 + l) * 8];
#pragma unroll
      for (int ct = 0; ct < 2; ++ct) {
        int frag = (2 * w + ct) * 64 + nt * 8 + kk;
        short8x b = *(const short8x*)(W2bf + ((size_t)frag * 512 + l * 8));
        acc2[0][ct] = __builtin_amdgcn_mfma_f32_16x16x32_bf16(a0, b, acc2[0][ct], 0, 0, 0);
        acc2[1][ct] = __builtin_amdgcn_mfma_f32_16x16x32_bf16(a1, b, acc2[1][ct], 0, 0, 0);
      }
    }
  }

  // ---- epilogue: + sum_e g[b,e]*b2[e,c], store fp32 (cols < 101 only)
#pragma unroll
  for (int ct = 0; ct < 2; ++ct) {
    int c = (2 * w + ct) * 16 + (l & 15);
    if (c < C_DIM) {
      float b2v[8];
#pragma unroll
      for (int e = 0; e < 8; ++e) b2v[e] = b2[e * C_DIM + c];
#pragma unroll
      for (int mt = 0; mt < 2; ++mt) {
#pragma unroll
        for (int r = 0; r < 4; ++r) {
          int row = mt * 16 + ((l >> 4) << 2) + r;
          float bias = 0.f;
#pragma unroll
          for (int e = 0; e < 8; ++e) bias += gates[row][e] * b2v[e];
          out[(size_t)(r0 + row) * C_DIM + c] = acc2[mt][ct][r] + bias;
        }
      }
    }
  }
}

extern "C" void kernel_launch(void* const* d_in, const int* in_sizes, int n_in,
                              void* d_out, int out_size, void* d_ws, size_t ws_size,
                              hipStream_t stream) {
  const float* x  = (const float*)d_in[0];
  const float* W1 = (const float*)d_in[1];
  const float* b1 = (const float*)d_in[2];
  const float* W2 = (const float*)d_in[3];
  const float* b2 = (const float*)d_in[4];
  const float* Wg = (const float*)d_in[5];
  const float* bg = (const float*)d_in[6];
  float* out = (float*)d_out;

  // workspace: W1bf = 129*16*512 u16 (2,113,536 B), then W2bf = 8*64*512 u16 (524,288 B)
  unsigned short* W1bf = (unsigned short*)d_ws;
  unsigned short* W2bf = (unsigned short*)((char*)d_ws + (size_t)129 * 16 * 512 * 2);

  conv_w1<<<516, 256, 0, stream>>>(W1, Wg, W1bf);   // 129*16*64 slots
  conv_w2<<<128, 256, 0, stream>>>(W2, W2bf);       // 8*64*64 slots
  moe_main<<<2048, 256, 0, stream>>>(x, b1, b2, bg, W1bf, W2bf, out);
}

// Round 2
// 491.300 us; speedup vs baseline: 1.2547x; 1.2547x over previous
//
#include <hip/hip_runtime.h>

// MoE fused kernel, MI355X gfx950 — Round 2: barrier-free main loop.
// Shapes: B=65536, D=512, C=101, E=8, H=256.
// out[b,c] = sum_{e,h} g[b,e]*relu(x@W1+b1)[b,e,h]*W2[e,h,c] + sum_e g[b,e]*b2[e,c]
// g = softmax(x@Wg+bg), gate logits folded into layer1 GEMM as cols 2048..2055.
//
// Round-2 restructure: layer2 is K-split across waves (each wave's own 64
// h-cols per nt), so the C->A transpose of h' is wave-private LDS (no
// __syncthreads in the nt loop). Cross-wave acc2 reduction happens once at
// the end. 2 barriers/nt -> 0; per-block barriers 19 -> 5.
//
// MFMA layouts (m89/m120-verified):
//   A: A[m][k], m=lane&15, k=(lane>>4)*8+j (j=0..7)
//   B: B[k][n], n=lane&15, k=(lane>>4)*8+j
//   C/D: col=lane&15, row=(lane>>4)*4+reg

typedef __attribute__((ext_vector_type(8))) short short8x;
typedef __attribute__((ext_vector_type(4))) float float4x;

#define C_DIM 101

__device__ __forceinline__ unsigned short f2bf(float f) {
  unsigned int u = __builtin_bit_cast(unsigned int, f);
  u += 0x7fffu + ((u >> 16) & 1u);     // round-to-nearest-even
  return (unsigned short)(u >> 16);
}

// ---- W1 (+Wg) -> bf16, B-frag packed: frag = ntile*16+kf ; elem = frag*512 + lane*8 + j
__global__ void conv_w1(const float* __restrict__ W1, const float* __restrict__ Wg,
                        unsigned short* __restrict__ out) {
  int s = blockIdx.x * blockDim.x + threadIdx.x;   // slot = frag*64 + lane
  int l = s & 63;
  int frag = s >> 6;
  int kf = frag & 15;
  int ntile = frag >> 4;
  int n = (ntile << 4) | (l & 15);
  int k = (kf << 5) | ((l >> 4) << 3);
  short8x v;
#pragma unroll
  for (int j = 0; j < 8; ++j) {
    int kk = k + j;
    float f;
    if (n < 2048)      f = W1[((size_t)(n >> 8) * 512 + kk) * 256 + (n & 255)];
    else if (n < 2056) f = Wg[(size_t)kk * 8 + (n - 2048)];
    else               f = 0.f;
    v[j] = (short)f2bf(f);
  }
  *(short8x*)(out + (size_t)s * 8) = v;
}

// ---- W2 -> bf16, B-frag packed: frag = ntile*64+kf ; ntile 0..7, kf 0..63 (K=2048)
__global__ void conv_w2(const float* __restrict__ W2, unsigned short* __restrict__ out) {
  int s = blockIdx.x * blockDim.x + threadIdx.x;
  int l = s & 63;
  int frag = s >> 6;
  int kf = frag & 63;
  int ntile = frag >> 6;
  int c = (ntile << 4) | (l & 15);
  int k = (kf << 5) | ((l >> 4) << 3);
  short8x v;
#pragma unroll
  for (int j = 0; j < 8; ++j) {
    int kk = k + j;                       // e = kk>>8, h = kk&255
    float f = (c < C_DIM) ? W2[((size_t)(kk >> 8) * 256 + (kk & 255)) * C_DIM + c] : 0.f;
    v[j] = (short)f2bf(f);
  }
  *(short8x*)(out + (size_t)s * 8) = v;
}

// ---- fused main kernel: 32 rows/block, 256 threads (4 waves)
__global__ __launch_bounds__(256, 3) void moe_main(
    const float* __restrict__ x, const float* __restrict__ b1,
    const float* __restrict__ b2, const float* __restrict__ bg,
    const unsigned short* __restrict__ W1bf, const unsigned short* __restrict__ W2bf,
    float* __restrict__ out) {
  __shared__ float4x pool4[3136];                         // 50176 B, 16B-aligned
  unsigned short* xA = (unsigned short*)pool4;            // [0,32K): x A-frag [mt*16+kf][64][8]
  unsigned short* hA = (unsigned short*)pool4 + 16384;    // [32K,48K): per-wave 4KB h' A-frags
  float* gatesf = (float*)((char*)pool4 + 49152);         // [48K,49K): gates [32][8]
  float* red = (float*)pool4;                             // reduction reuses [0,48K)

  const int tid = threadIdx.x;
  const int w = tid >> 6;     // wave 0..3
  const int l = tid & 63;     // lane
  const int quad = l >> 4;
  const int r0 = blockIdx.x * 32;
  unsigned short* hAw = hA + w * 2048;                    // wave-private 4 KB

  // ---- stage x -> bf16 A-frag LDS (coalesced float4 x2 reads, b128 LDS writes)
#pragma unroll
  for (int it = 0; it < 8; ++it) {
    int g = tid + it * 256;            // m = g>>6, k0 = (g&63)*8
    int m = g >> 6;
    int k0 = (g & 63) << 3;
    const float* src = x + (size_t)(r0 + m) * 512 + k0;
    float4 f0 = *(const float4*)src;
    float4 f1 = *(const float4*)(src + 4);
    short8x v;
    v[0] = (short)f2bf(f0.x); v[1] = (short)f2bf(f0.y);
    v[2] = (short)f2bf(f0.z); v[3] = (short)f2bf(f0.w);
    v[4] = (short)f2bf(f1.x); v[5] = (short)f2bf(f1.y);
    v[6] = (short)f2bf(f1.z); v[7] = (short)f2bf(f1.w);
    int mt = m >> 4;
    int kfrag = k0 >> 5;
    int lane = (((k0 >> 3) & 3) << 4) | (m & 15);
    *(short8x*)&xA[(size_t)(((mt << 4) | kfrag) * 64 + lane) * 8] = v;
  }
  __syncthreads();

  // ---- gate logits: waves 0,1 each do one 16-row tile x 16 gate cols (ntile 128)
  if (w < 2) {
    float4x acc = {0.f, 0.f, 0.f, 0.f};
    for (int kf = 0; kf < 16; ++kf) {
      short8x a = *(const short8x*)&xA[(size_t)((w * 16 + kf) * 64 + l) * 8];
      short8x b = *(const short8x*)(W1bf + ((size_t)(128 * 16 + kf) * 512 + l * 8));
      acc = __builtin_amdgcn_mfma_f32_16x16x32_bf16(a, b, acc, 0, 0, 0);
    }
    int col = l & 15;
    if (col < 8) {
      float bgv = bg[col];
#pragma unroll
      for (int r = 0; r < 4; ++r) {
        int row = (quad << 2) + r;
        gatesf[(w * 16 + row) * 8 + col] = acc[r] + bgv;
      }
    }
  }
  __syncthreads();
  // softmax over E=8 per row, fp32
  if (tid < 32) {
    float v[8], mx = -1e30f;
#pragma unroll
    for (int e = 0; e < 8; ++e) { v[e] = gatesf[tid * 8 + e]; mx = fmaxf(mx, v[e]); }
    float s = 0.f;
#pragma unroll
    for (int e = 0; e < 8; ++e) { v[e] = expf(v[e] - mx); s += v[e]; }
    float inv = 1.f / s;
#pragma unroll
    for (int e = 0; e < 8; ++e) gatesf[tid * 8 + e] = v[e] * inv;
  }
  __syncthreads();

  // ---- main loop over 8 N-tiles of 256 h-columns (expert e == nt), NO barriers
  float4x zero = {0.f, 0.f, 0.f, 0.f};
  float4x acc2[2][8];                    // layer2 partial: rows mt*16.., cols ct*16..
#pragma unroll
  for (int mt = 0; mt < 2; ++mt)
#pragma unroll
    for (int ct = 0; ct < 8; ++ct) acc2[mt][ct] = zero;

  for (int nt = 0; nt < 8; ++nt) {
    // layer1: wave w covers cols [w*64, w*64+64) of this N-tile; all 32 rows
    float4x acc1[2][4];
#pragma unroll
    for (int mt = 0; mt < 2; ++mt)
#pragma unroll
      for (int nc = 0; nc < 4; ++nc) acc1[mt][nc] = zero;
#pragma unroll 2
    for (int kf = 0; kf < 16; ++kf) {
      short8x a0 = *(const short8x*)&xA[(size_t)((0 * 16 + kf) * 64 + l) * 8];
      short8x a1 = *(const short8x*)&xA[(size_t)((1 * 16 + kf) * 64 + l) * 8];
#pragma unroll
      for (int nc = 0; nc < 4; ++nc) {
        int ntile = nt * 16 + w * 4 + nc;
        short8x b = *(const short8x*)(W1bf + ((size_t)(ntile * 16 + kf) * 512 + l * 8));
        acc1[0][nc] = __builtin_amdgcn_mfma_f32_16x16x32_bf16(a0, b, acc1[0][nc], 0, 0, 0);
        acc1[1][nc] = __builtin_amdgcn_mfma_f32_16x16x32_bf16(a1, b, acc1[1][nc], 0, 0, 0);
      }
    }

    // epilogue: +b1, relu, *gate(e==nt), bf16 -> wave-private hA (C->A transpose)
    float gv0[4], gv1[4];
#pragma unroll
    for (int r = 0; r < 4; ++r) {
      gv0[r] = gatesf[(quad * 4 + r) * 8 + nt];
      gv1[r] = gatesf[(16 + quad * 4 + r) * 8 + nt];
    }
#pragma unroll
    for (int nc = 0; nc < 4; ++nc) {
      int cin = nc * 16 + (l & 15);                      // col within wave's 64
      int n = nt * 256 + w * 64 + cin;                   // global h-col
      float b1v = b1[n];
      int kkl = cin >> 5;
      int jj = cin & 7;
      int chunk = (cin >> 3) & 3;
#pragma unroll
      for (int mt = 0; mt < 2; ++mt) {
#pragma unroll
        for (int r = 0; r < 4; ++r) {
          float gvv = mt ? gv1[r] : gv0[r];
          float hv = fmaxf(acc1[mt][nc][r] + b1v, 0.f) * gvv;
          int ld = (quad * 4 + r) + (chunk << 4);
          hAw[(mt * 2 + kkl) * 512 + ld * 8 + jj] = f2bf(hv);
        }
      }
    }

    // layer2 partial: K-slice = this wave's 64 h-cols, ALL 8 output col-tiles
#pragma unroll
    for (int kkl = 0; kkl < 2; ++kkl) {
      short8x a0 = *(const short8x*)&hAw[(0 * 2 + kkl) * 512 + l * 8];
      short8x a1 = *(const short8x*)&hAw[(1 * 2 + kkl) * 512 + l * 8];
      int kf2 = nt * 8 + w * 2 + kkl;
#pragma unroll
      for (int ct = 0; ct < 8; ++ct) {
        short8x b = *(const short8x*)(W2bf + ((size_t)(ct * 64 + kf2) * 512 + l * 8));
        acc2[0][ct] = __builtin_amdgcn_mfma_f32_16x16x32_bf16(a0, b, acc2[0][ct], 0, 0, 0);
        acc2[1][ct] = __builtin_amdgcn_mfma_f32_16x16x32_bf16(a1, b, acc2[1][ct], 0, 0, 0);
      }
    }
  }

  // ---- cross-wave reduction of acc2 partials (once per block)
  __syncthreads();                       // everyone done with xA/hA
  // non-owners write partials: red[ct][slot(3)][mt][lane][4]
#pragma unroll
  for (int ct = 0; ct < 8; ++ct) {
    int ow = ct >> 1;
    if (ow != w) {
      int s = w - (w > ow ? 1 : 0);
#pragma unroll
      for (int mt = 0; mt < 2; ++mt)
        *(float4x*)&red[((((ct * 3) + s) * 2 + mt) * 64 + l) * 4] = acc2[mt][ct];
    }
  }
  __syncthreads();
  // owner (wave w owns ct = 2w, 2w+1): accumulate, add gate-weighted b2, store
#pragma unroll
  for (int ctl = 0; ctl < 2; ++ctl) {
    int ct = w * 2 + ctl;
    int c = ct * 16 + (l & 15);
    float4x f0 = acc2[0][ct];
    float4x f1 = acc2[1][ct];
#pragma unroll
    for (int s = 0; s < 3; ++s) {
      f0 += *(const float4x*)&red[((((ct * 3) + s) * 2 + 0) * 64 + l) * 4];
      f1 += *(const float4x*)&red[((((ct * 3) + s) * 2 + 1) * 64 + l) * 4];
    }
    if (c < C_DIM) {
      float b2v[8];
#pragma unroll
      for (int e = 0; e < 8; ++e) b2v[e] = b2[e * C_DIM + c];
#pragma unroll
      for (int mt = 0; mt < 2; ++mt) {
#pragma unroll
        for (int r = 0; r < 4; ++r) {
          int row = mt * 16 + quad * 4 + r;
          float bias = 0.f;
#pragma unroll
          for (int e = 0; e < 8; ++e) bias += gatesf[row * 8 + e] * b2v[e];
          float val = (mt ? f1[r] : f0[r]) + bias;
          out[(size_t)(r0 + row) * C_DIM + c] = val;
        }
      }
    }
  }
}

extern "C" void kernel_launch(void* const* d_in, const int* in_sizes, int n_in,
                              void* d_out, int out_size, void* d_ws, size_t ws_size,
                              hipStream_t stream) {
  const float* x  = (const float*)d_in[0];
  const float* W1 = (const float*)d_in[1];
  const float* b1 = (const float*)d_in[2];
  const float* W2 = (const float*)d_in[3];
  const float* b2 = (const float*)d_in[4];
  const float* Wg = (const float*)d_in[5];
  const float* bg = (const float*)d_in[6];
  float* out = (float*)d_out;

  unsigned short* W1bf = (unsigned short*)d_ws;
  unsigned short* W2bf = (unsigned short*)((char*)d_ws + (size_t)129 * 16 * 512 * 2);

  conv_w1<<<516, 256, 0, stream>>>(W1, Wg, W1bf);   // 129*16*64 slots
  conv_w2<<<128, 256, 0, stream>>>(W2, W2bf);       // 8*64*64 slots
  moe_main<<<2048, 256, 0, stream>>>(x, b1, b2, bg, W1bf, W2bf, out);
}

// Round 3
// 482.221 us; speedup vs baseline: 1.2783x; 1.0188x over previous
//
#include <hip/hip_runtime.h>

// MoE fused kernel, MI355X gfx950 — Round 3: Mtile=64, 512 threads, no spills.
// Shapes: B=65536, D=512, C=101, E=8, H=256.
// out[b,c] = sum_{e,h} g[b,e]*relu(x@W1+b1)[b,e,h]*W2[e,h,c] + sum_e g[b,e]*b2[e,c]
// g = softmax(x@Wg+bg), gate logits folded into layer1 GEMM as cols 2048..2055.
//
// R3: Mtile 32->64 (each B fragment reused by 4 row-tiles: halves L2 B-frag
// traffic, the ~150us floor of R2). 8 waves/block; layer2 K-split: wave w owns
// h-cols [nt*256 + w*32, +32) as its K-slice for ALL 8 output col-tiles ->
// wave-private transpose LDS, zero nt-loop barriers. acc2[4][8]=128 +
// acc1[4][2]=32 accumulator VGPRs under launch_bounds(512,2)'s 256-reg cap
// (R2's spill: 172 > 168 cap -> 136MB scratch writes).
//
// MFMA layouts (m89/m120-verified):
//   A: A[m][k], m=lane&15, k=(lane>>4)*8+j (j=0..7)
//   B: B[k][n], n=lane&15, k=(lane>>4)*8+j
//   C/D: col=lane&15, row=(lane>>4)*4+reg

typedef __attribute__((ext_vector_type(8))) short short8x;
typedef __attribute__((ext_vector_type(4))) float float4x;

#define C_DIM 101

__device__ __forceinline__ unsigned short f2bf(float f) {
  unsigned int u = __builtin_bit_cast(unsigned int, f);
  u += 0x7fffu + ((u >> 16) & 1u);     // round-to-nearest-even
  return (unsigned short)(u >> 16);
}

// ---- W1 (+Wg) -> bf16, B-frag packed: frag = ntile*16+kf ; elem = frag*512 + lane*8 + j
__global__ void conv_w1(const float* __restrict__ W1, const float* __restrict__ Wg,
                        unsigned short* __restrict__ out) {
  int s = blockIdx.x * blockDim.x + threadIdx.x;   // slot = frag*64 + lane
  int l = s & 63;
  int frag = s >> 6;
  int kf = frag & 15;
  int ntile = frag >> 4;
  int n = (ntile << 4) | (l & 15);
  int k = (kf << 5) | ((l >> 4) << 3);
  short8x v;
#pragma unroll
  for (int j = 0; j < 8; ++j) {
    int kk = k + j;
    float f;
    if (n < 2048)      f = W1[((size_t)(n >> 8) * 512 + kk) * 256 + (n & 255)];
    else if (n < 2056) f = Wg[(size_t)kk * 8 + (n - 2048)];
    else               f = 0.f;
    v[j] = (short)f2bf(f);
  }
  *(short8x*)(out + (size_t)s * 8) = v;
}

// ---- W2 -> bf16, B-frag packed: frag = ntile*64+kf ; ntile 0..7, kf 0..63 (K=2048)
__global__ void conv_w2(const float* __restrict__ W2, unsigned short* __restrict__ out) {
  int s = blockIdx.x * blockDim.x + threadIdx.x;
  int l = s & 63;
  int frag = s >> 6;
  int kf = frag & 63;
  int ntile = frag >> 6;
  int c = (ntile << 4) | (l & 15);
  int k = (kf << 5) | ((l >> 4) << 3);
  short8x v;
#pragma unroll
  for (int j = 0; j < 8; ++j) {
    int kk = k + j;                       // e = kk>>8, h = kk&255
    float f = (c < C_DIM) ? W2[((size_t)(kk >> 8) * 256 + (kk & 255)) * C_DIM + c] : 0.f;
    v[j] = (short)f2bf(f);
  }
  *(short8x*)(out + (size_t)s * 8) = v;
}

// ---- fused main kernel: 64 rows/block, 512 threads (8 waves)
__global__ __launch_bounds__(512, 2) void moe_main(
    const float* __restrict__ x, const float* __restrict__ b1,
    const float* __restrict__ b2, const float* __restrict__ bg,
    const unsigned short* __restrict__ W1bf, const unsigned short* __restrict__ W2bf,
    float* __restrict__ out) {
  __shared__ float4x pool4[6400];                         // 102400 B
  unsigned short* xA = (unsigned short*)pool4;            // [0,64K): x A-frag [mt*16+kf][64][8]
  unsigned short* hA = xA + 32768;                        // [64K,96K): 8 x 4KB wave-private h'
  float* graw = (float*)((char*)pool4 + 98304);           // [96K,98K): raw logits [64][8]
  float* gt   = (float*)((char*)pool4 + 100352);          // [98K,100K): gates^T [8][64]
  float* red  = (float*)pool4;                            // reduction reuses [0,56K)

  const int tid = threadIdx.x;
  const int w = tid >> 6;     // wave 0..7
  const int l = tid & 63;     // lane
  const int quad = l >> 4;
  const int r0 = blockIdx.x * 64;
  unsigned short* hAw = hA + w * 2048;                    // wave-private 4 KB

  // ---- stage x -> bf16 A-frag LDS (coalesced float4 x2 reads, b128 LDS writes)
#pragma unroll
  for (int it = 0; it < 8; ++it) {
    int g = tid + it * 512;            // m = g>>6 (0..63), k0 = (g&63)*8
    int m = g >> 6;
    int k0 = (g & 63) << 3;
    const float* src = x + (size_t)(r0 + m) * 512 + k0;
    float4 f0 = *(const float4*)src;
    float4 f1 = *(const float4*)(src + 4);
    short8x v;
    v[0] = (short)f2bf(f0.x); v[1] = (short)f2bf(f0.y);
    v[2] = (short)f2bf(f0.z); v[3] = (short)f2bf(f0.w);
    v[4] = (short)f2bf(f1.x); v[5] = (short)f2bf(f1.y);
    v[6] = (short)f2bf(f1.z); v[7] = (short)f2bf(f1.w);
    int mt = m >> 4;
    int kfrag = k0 >> 5;
    int lane = (((k0 >> 3) & 3) << 4) | (m & 15);
    *(short8x*)&xA[(size_t)(((mt << 4) | kfrag) * 64 + lane) * 8] = v;
  }
  __syncthreads();

  // ---- gate logits: waves 0..3 each do one 16-row tile x 16 gate cols (ntile 128)
  if (w < 4) {
    float4x acc = {0.f, 0.f, 0.f, 0.f};
    for (int kf = 0; kf < 16; ++kf) {
      short8x a = *(const short8x*)&xA[(size_t)((w * 16 + kf) * 64 + l) * 8];
      short8x b = *(const short8x*)(W1bf + ((size_t)(128 * 16 + kf) * 512 + l * 8));
      acc = __builtin_amdgcn_mfma_f32_16x16x32_bf16(a, b, acc, 0, 0, 0);
    }
    int col = l & 15;
    if (col < 8) {
      float bgv = bg[col];
#pragma unroll
      for (int r = 0; r < 4; ++r) {
        int row = (quad << 2) + r;
        graw[(w * 16 + row) * 8 + col] = acc[r] + bgv;
      }
    }
  }
  __syncthreads();
  // softmax over E=8 per row, fp32; write transposed gt[e][row]
  if (tid < 64) {
    float v[8], mx = -1e30f;
#pragma unroll
    for (int e = 0; e < 8; ++e) { v[e] = graw[tid * 8 + e]; mx = fmaxf(mx, v[e]); }
    float s = 0.f;
#pragma unroll
    for (int e = 0; e < 8; ++e) { v[e] = expf(v[e] - mx); s += v[e]; }
    float inv = 1.f / s;
#pragma unroll
    for (int e = 0; e < 8; ++e) gt[e * 64 + tid] = v[e] * inv;
  }
  __syncthreads();

  // ---- main loop over 8 N-tiles of 256 h-columns (expert e == nt), NO barriers
  float4x zero = {0.f, 0.f, 0.f, 0.f};
  float4x acc2[4][8];                    // layer2 partial: rows mt*16.., cols ct*16..
#pragma unroll
  for (int mt = 0; mt < 4; ++mt)
#pragma unroll
    for (int ct = 0; ct < 8; ++ct) acc2[mt][ct] = zero;

  for (int nt = 0; nt < 8; ++nt) {
    // layer1: wave w covers h-cols [nt*256 + w*32, +32); all 64 rows
    float4x acc1[4][2];
#pragma unroll
    for (int mt = 0; mt < 4; ++mt)
#pragma unroll
      for (int nc = 0; nc < 2; ++nc) acc1[mt][nc] = zero;
#pragma unroll 2
    for (int kf = 0; kf < 16; ++kf) {
      short8x a0 = *(const short8x*)&xA[(size_t)((0 * 16 + kf) * 64 + l) * 8];
      short8x a1 = *(const short8x*)&xA[(size_t)((1 * 16 + kf) * 64 + l) * 8];
      short8x a2 = *(const short8x*)&xA[(size_t)((2 * 16 + kf) * 64 + l) * 8];
      short8x a3 = *(const short8x*)&xA[(size_t)((3 * 16 + kf) * 64 + l) * 8];
#pragma unroll
      for (int nc = 0; nc < 2; ++nc) {
        int ntile = nt * 16 + w * 2 + nc;
        short8x b = *(const short8x*)(W1bf + ((size_t)(ntile * 16 + kf) * 512 + l * 8));
        acc1[0][nc] = __builtin_amdgcn_mfma_f32_16x16x32_bf16(a0, b, acc1[0][nc], 0, 0, 0);
        acc1[1][nc] = __builtin_amdgcn_mfma_f32_16x16x32_bf16(a1, b, acc1[1][nc], 0, 0, 0);
        acc1[2][nc] = __builtin_amdgcn_mfma_f32_16x16x32_bf16(a2, b, acc1[2][nc], 0, 0, 0);
        acc1[3][nc] = __builtin_amdgcn_mfma_f32_16x16x32_bf16(a3, b, acc1[3][nc], 0, 0, 0);
      }
    }

    // epilogue: +b1, relu, *gate(e==nt), bf16 -> wave-private hA (C->A transpose)
    float4x gv[4];
#pragma unroll
    for (int mt = 0; mt < 4; ++mt)
      gv[mt] = *(const float4x*)&gt[nt * 64 + mt * 16 + quad * 4];
#pragma unroll
    for (int nc = 0; nc < 2; ++nc) {
      int cin = nc * 16 + (l & 15);                      // col within wave's 32
      int n = nt * 256 + w * 32 + cin;                   // global h-col
      float b1v = b1[n];
      int jj = cin & 7;
      int chunk = cin >> 3;                              // 0..3 (A-frag quad)
#pragma unroll
      for (int mt = 0; mt < 4; ++mt) {
#pragma unroll
        for (int r = 0; r < 4; ++r) {
          float hv = fmaxf(acc1[mt][nc][r] + b1v, 0.f) * gv[mt][r];
          int ld = (chunk << 4) + quad * 4 + r;          // A-frag lane
          hAw[mt * 512 + ld * 8 + jj] = f2bf(hv);
        }
      }
    }

    // layer2 partial: K-slice = this wave's 32 h-cols (one K-frag), all 8 ct
    int kf2 = nt * 8 + w;
    short8x a20 = *(const short8x*)&hAw[0 * 512 + l * 8];
    short8x a21 = *(const short8x*)&hAw[1 * 512 + l * 8];
    short8x a22 = *(const short8x*)&hAw[2 * 512 + l * 8];
    short8x a23 = *(const short8x*)&hAw[3 * 512 + l * 8];
#pragma unroll
    for (int ct = 0; ct < 8; ++ct) {
      short8x b = *(const short8x*)(W2bf + ((size_t)(ct * 64 + kf2) * 512 + l * 8));
      acc2[0][ct] = __builtin_amdgcn_mfma_f32_16x16x32_bf16(a20, b, acc2[0][ct], 0, 0, 0);
      acc2[1][ct] = __builtin_amdgcn_mfma_f32_16x16x32_bf16(a21, b, acc2[1][ct], 0, 0, 0);
      acc2[2][ct] = __builtin_amdgcn_mfma_f32_16x16x32_bf16(a22, b, acc2[2][ct], 0, 0, 0);
      acc2[3][ct] = __builtin_amdgcn_mfma_f32_16x16x32_bf16(a23, b, acc2[3][ct], 0, 0, 0);
    }
  }

  // ---- cross-wave reduction of acc2 (4 phases over mt), then store
  int c = w * 16 + (l & 15);            // wave w owns output col-tile ct=w
  float b2v[8];
#pragma unroll
  for (int e = 0; e < 8; ++e) b2v[e] = (c < C_DIM) ? b2[e * C_DIM + c] : 0.f;

  __syncthreads();                      // all waves done with xA before red reuse
#pragma unroll
  for (int mt = 0; mt < 4; ++mt) {
#pragma unroll
    for (int ct = 0; ct < 8; ++ct) {
      if (ct != w) {
        int s = w - (w > ct ? 1 : 0);   // 0..6
        *(float4x*)&red[((ct * 7 + s) * 64 + l) * 4] = acc2[mt][ct];
      }
    }
    __syncthreads();
    float4x sum = acc2[mt][w];
#pragma unroll
    for (int s = 0; s < 7; ++s)
      sum += *(const float4x*)&red[((w * 7 + s) * 64 + l) * 4];
    if (c < C_DIM) {
#pragma unroll
      for (int r = 0; r < 4; ++r) {
        int row = mt * 16 + quad * 4 + r;
        float bias = 0.f;
#pragma unroll
        for (int e = 0; e < 8; ++e) bias += gt[e * 64 + row] * b2v[e];
        out[(size_t)(r0 + row) * C_DIM + c] = sum[r] + bias;
      }
    }
    __syncthreads();                    // reads done before next phase overwrites red
  }
}

extern "C" void kernel_launch(void* const* d_in, const int* in_sizes, int n_in,
                              void* d_out, int out_size, void* d_ws, size_t ws_size,
                              hipStream_t stream) {
  const float* x  = (const float*)d_in[0];
  const float* W1 = (const float*)d_in[1];
  const float* b1 = (const float*)d_in[2];
  const float* W2 = (const float*)d_in[3];
  const float* b2 = (const float*)d_in[4];
  const float* Wg = (const float*)d_in[5];
  const float* bg = (const float*)d_in[6];
  float* out = (float*)d_out;

  unsigned short* W1bf = (unsigned short*)d_ws;
  unsigned short* W2bf = (unsigned short*)((char*)d_ws + (size_t)129 * 16 * 512 * 2);

  conv_w1<<<516, 256, 0, stream>>>(W1, Wg, W1bf);   // 129*16*64 slots
  conv_w2<<<128, 256, 0, stream>>>(W2, W2bf);       // 8*64*64 slots
  moe_main<<<1024, 512, 0, stream>>>(x, b1, b2, bg, W1bf, W2bf, out);
}